// Round 7
// baseline (87.424 us; speedup 1.0000x reference)
//
#include <hip/hip_runtime.h>

#define GH 52
#define GW 52
#define NB 5
#define NCELL (GH*GW)        // 2704
#define NBOX (NCELL*NB)      // 13520
#define SCALE 8.0f           // 416/52
#define NORMY 416.0f
#define IOU_T 0.4f

// ---- decode tile geometry: 13 wide x 4 tall, 52 blocks (R2-proven) ----
#define TSX 13
#define TSY 4
#define HSX (TSX+2)          // 15
#define HSY (TSY+2)          // 6
#define TBOX (HSX*HSY*NB)    // 450 staged boxes
#define NTX (GW/TSX)         // 4
#define NTY (GH/TSY)         // 13
#define NDEC (NTX*NTY)       // 52 decode blocks

// ---- nms geometry: 13 waves x 4-row bands, column-per-lane in registers ----
#define PW2 56               // padded act row stride (bytes)
#define PR  54               // padded rows
#define PC2 (PR*PW2)         // 3024 B
#define NWAVE 13
#define BLK 832              // 13 waves
#define MAGIC 0x5A17C3E9u
#define MASK45 ((1ull<<45)-1)

// One dispatch: blocks 0..51 decode (coords->out, masks+scores->ws, publish
// flag), block 52 runs the NMS fixpoint after spinning on the 52 flags.
// Scores are written ONLY by the nms block (sole-writer: replay-safe, R2-proven).
__global__ __launch_bounds__(BLK) void fused_kernel(
        const float* __restrict__ x, float* __restrict__ out,
        unsigned long long* __restrict__ masks,
        float* __restrict__ wscore,
        unsigned int* __restrict__ ready) {
    __shared__ float4 lbox[TBOX];
    __shared__ float  lsc[TBOX];
    __shared__ unsigned char act_s[PC2];
    __shared__ unsigned wf[3][16];           // wave-dirty flags, 3-slot rotation

    int t = threadIdx.x;

    if (blockIdx.x < NDEC) {
        // ---------------- decode + suppression-mask build ----------------
        int bx0 = (blockIdx.x % NTX) * TSX;
        int by0 = (blockIdx.x / NTX) * TSY;

        if (t < TBOX) {
            int lcell = t / NB, b = t - lcell * NB;
            int lx = lcell % HSX, ly = lcell / HSX;
            int gx = bx0 + lx - 1, gy = by0 + ly - 1;
            float4 bb = make_float4(0.f, 0.f, 0.f, 0.f);
            float s = -1e30f;                  // sentinel: never a predecessor
            if (gx >= 0 && gx < GW && gy >= 0 && gy < GH) {
                const float* p = x + ((size_t)(gy * GW + gx) * NB + b) * 5;
                float c0 = p[0], c1 = p[1], c2 = p[2], c3 = p[3]; s = p[4];
                float cx = (c0 + (float)gx) * SCALE;
                float w  = c2 * SCALE;
                float cy = NORMY - (c1 + (float)gy) * SCALE;
                float h  = c3 * SCALE;
                bb = make_float4(cx - w * 0.5f, cy - h * 0.5f,
                                 cx + w * 0.5f, cy + h * 0.5f);
            }
            lbox[t] = bb; lsc[t] = s;
        }
        __syncthreads();

        if (t < TSX * TSY * NB) {              // 260 interior boxes
            int lcell = t / NB, b = t - lcell * NB;
            int lxi = lcell % TSX, lyi = lcell / TSX;
            int gx = bx0 + lxi, gy = by0 + lyi;
            int lt = ((lyi + 1) * HSX + (lxi + 1)) * NB + b;
            float4 bj = lbox[lt]; float sj = lsc[lt];
            int cell = gy * GW + gx;
            int j = cell * NB + b;
            float areaj = fmaxf(bj.z - bj.x, 0.f) * fmaxf(bj.w - bj.y, 0.f);
            unsigned long long m = 0ull;
            #pragma unroll
            for (int dy = -1; dy <= 1; ++dy)
            #pragma unroll
            for (int dx = -1; dx <= 1; ++dx)
            #pragma unroll
            for (int nb2 = 0; nb2 < NB; ++nb2) {
                int ln = ((lyi + 1 + dy) * HSX + (lxi + 1 + dx)) * NB + nb2;
                int i = j + (dy * GW + dx) * NB + (nb2 - b);
                if (i == j) continue;
                float si = lsc[ln];
                // pri(i) > pri(j): score desc, stable-argsort index-asc tiebreak
                bool earlier = (si > sj) || (si == sj && i < j);
                if (!earlier) continue;
                float4 bi = lbox[ln];
                float iw = fmaxf(fminf(bi.z, bj.z) - fmaxf(bi.x, bj.x), 0.f);
                float ih = fmaxf(fminf(bi.w, bj.w) - fmaxf(bi.y, bj.y), 0.f);
                float inter = iw * ih;
                float areai = fmaxf(bi.z - bi.x, 0.f) * fmaxf(bi.w - bi.y, 0.f);
                float uni = areai + areaj - inter;
                float iou = (uni > 0.f) ? inter / fmaxf(uni, 1e-12f) : 0.f;
                if (iou > IOU_T)
                    m |= 1ull << ((dy + 1) * 15 + (dx + 1) * 5 + nb2);
            }
            masks[b * NCELL + cell] = m;       // plane-major for nms coalescing
            out[j * 5 + 0] = bj.x; out[j * 5 + 1] = bj.y;
            out[j * 5 + 2] = bj.z; out[j * 5 + 3] = bj.w;
            wscore[j] = sj;
        }
        __syncthreads();
        if (t == 0) {
            __threadfence();
            __hip_atomic_store(&ready[blockIdx.x], MAGIC,
                               __ATOMIC_RELEASE, __HIP_MEMORY_SCOPE_AGENT);
        }
        return;
    }

    // ---------------- nms block: band-in-register fixpoint ----------------
    // Wave w owns global rows R0..R0+3; lane l (<52) owns the 4-cell column at
    // col l, packed in cs: bits 0-4 = top halo row (R0-1), 5(i+1)..+4 = cell i,
    // bits 25-29 = bottom halo row (R0+4). Inner iterations exchange neighbor
    // columns via __shfl (registers only; no LDS, no barrier): horizontal
    // chains resolve fully within one outer round; vertical-within-band via
    // in-register Gauss-Seidel. Outer rounds exchange band-boundary rows via
    // LDS + 1 barrier, gated by wave-dirty flags (3-buffer rotation, proven).
    // Frozen halos are chaotic-iteration-safe: any change is re-flagged; a
    // zero-change global round (syncthreads_count==0) certifies the fixpoint.
    int l = t & 63, w = t >> 6;
    bool wk = l < GW;                    // 52 worker lanes per wave
    int R0 = w * 4;

    for (int i = t; i < PC2; i += BLK) {
        int py = i / PW2, px = i - py * PW2;
        act_s[i] = (py >= 1 && py <= GH && px >= 1 && px <= GW) ? 0x1F : 0;
    }
    if (t < 16) {
        wf[0][t] = 0; wf[1][t] = 0;
        wf[2][t] = (t >= 1 && t <= NWAVE) ? 1u : 0u;   // prev for round 0: all dirty
    }

    // wait for all decode blocks (ws re-poisoned each iteration -> spin valid)
    if (t < NDEC) {
        while (__hip_atomic_load(&ready[t], __ATOMIC_ACQUIRE,
                                 __HIP_MEMORY_SCOPE_AGENT) != MAGIC) {}
    }
    __syncthreads();

    // owned masks -> registers (plane-major: lane-consecutive u64, coalesced)
    unsigned long long cm[4][NB];
    #pragma unroll
    for (int i = 0; i < 4; ++i)
        #pragma unroll
        for (int b = 0; b < NB; ++b)
            cm[i][b] = wk ? (masks[b * NCELL + (R0 + i) * GW + l] & MASK45) : 0ull;

    unsigned cs = wk ? ((0x1Fu << 5) | (0x1Fu << 10) | (0x1Fu << 15) | (0x1Fu << 20))
                     : 0u;

    int pprev = 2, pcur = 0, pnext = 1;
    for (int round = 0; round < 128; ++round) {
        if (t < 16) wf[pnext][t] = 0;        // clear next slot (unused this round)
        bool dirty = (wf[pprev][w] | wf[pprev][w + 1] | wf[pprev][w + 2]) != 0u;
        bool mych = false;
        unsigned chm = 0;
        if (dirty) {
            if (wk) {                         // refresh frozen halo rows
                unsigned top = act_s[R0 * PW2 + l + 1];        // global row R0-1
                unsigned bot = act_s[(R0 + 5) * PW2 + l + 1];  // global row R0+4
                cs = (cs & 0x01FFFFE0u) | top | (bot << 25);
            }
            for (int it = 0; it < 64; ++it) {
                unsigned Lc = __shfl(cs, (l == 0) ? 0 : (l - 1));
                if (l == 0) Lc = 0u;
                unsigned Rc = __shfl(cs, (l >= 51) ? 51 : (l + 1));
                if (l >= 51) Rc = 0u;
                bool ch = false;
                if (wk) {
                    auto mkrow = [&](int k) -> unsigned {
                        unsigned s = 5u * k;
                        return ((Lc >> s) & 31u)
                             | (((cs >> s) & 31u) << 5)
                             | (((Rc >> s) & 31u) << 10);
                    };
                    unsigned long long V = (unsigned long long)mkrow(0)
                        | ((unsigned long long)mkrow(1) << 15)
                        | ((unsigned long long)mkrow(2) << 30);
                    #pragma unroll
                    for (int i = 0; i < 4; ++i) {
                        if (i) V = (V >> 15) | ((unsigned long long)mkrow(i + 2) << 30);
                        unsigned nb = (unsigned)((V & cm[i][0]) == 0ull)
                                    | ((unsigned)((V & cm[i][1]) == 0ull) << 1)
                                    | ((unsigned)((V & cm[i][2]) == 0ull) << 2)
                                    | ((unsigned)((V & cm[i][3]) == 0ull) << 3)
                                    | ((unsigned)((V & cm[i][4]) == 0ull) << 4);
                        unsigned pos = 5u * (i + 1);
                        unsigned old = (cs >> pos) & 31u;
                        if (nb != old) {
                            cs ^= (old ^ nb) << pos;       // vertical Gauss-Seidel
                            V  ^= (unsigned long long)(old ^ nb) << 20; // mid-row C slot
                            ch = true; chm |= 1u << i;
                        }
                    }
                }
                mych |= ch;
                if (!__any(ch)) break;        // band-internal fixpoint reached
            }
            if (wk && chm) {
                #pragma unroll
                for (int i = 0; i < 4; ++i)
                    if ((chm >> i) & 1u)
                        act_s[(R0 + i + 1) * PW2 + l + 1] =
                            (unsigned char)((cs >> (5 * (i + 1))) & 31u);
            }
            bool wch = __any(mych);
            if (l == 0 && wch) wf[pcur][w + 1] = 1u;   // single writer per word
        }
        if (__syncthreads_count(mych ? 1 : 0) == 0) break;
        int t0 = pprev; pprev = pcur; pcur = pnext; pnext = t0;
    }

    // writeback: nms block is the sole writer of the score field
    if (wk) {
        #pragma unroll
        for (int i = 0; i < 4; ++i) {
            unsigned bits = (cs >> (5 * (i + 1))) & 31u;
            int j0 = ((R0 + i) * GW + l) * NB;
            #pragma unroll
            for (int b = 0; b < NB; ++b)
                out[(j0 + b) * 5 + 4] = ((bits >> b) & 1u) ? wscore[j0 + b] : 0.0f;
        }
    }
}

extern "C" void kernel_launch(void* const* d_in, const int* in_sizes, int n_in,
                              void* d_out, int out_size, void* d_ws, size_t ws_size,
                              hipStream_t stream) {
    const float* x = (const float*)d_in[0];
    float* out = (float*)d_out;

    // ws: masks u64[NB][NCELL] plane-major (108160 B) | wscore f32[NBOX]
    //     (54080 B) | ready u32[52]
    unsigned long long* masks = (unsigned long long*)d_ws;
    float* wscore = (float*)((char*)d_ws + 108160);
    unsigned int* ready = (unsigned int*)((char*)d_ws + 108160 + 54080);

    fused_kernel<<<NDEC + 1, BLK, 0, stream>>>(x, out, masks, wscore, ready);
}